// Round 1
// baseline (35617.831 us; speedup 1.0000x reference)
//
#include <hip/hip_runtime.h>
#include <hip/hip_bf16.h>
#include <math.h>

// Problem constants
#define QLEN   512
#define MLEN   512
#define KLEN   1024
#define BSZ    8
#define NH     16
#define DH     64
#define DM     1024
#define DI     4096
#define NTOK   32000
#define NROW   4096      // QLEN*BSZ
#define XROW   8192      // KLEN*BSZ
#define VTILES 500       // 32000/64

// ---------------------------------------------------------------------------
// Positional embedding: pos[j, d], j=0..1023, pos_seq[j] = 1023-j
// d<512: sin(pos_seq*inv_freq[d]); d>=512: cos(pos_seq*inv_freq[d-512])
// inv_freq[k] = 10000^{-2k/1024}
__global__ __launch_bounds__(256) void pos_kernel(float* __restrict__ pos) {
    int j = blockIdx.x;
    int t = threadIdx.x;
    float p = (float)(1023 - j);
    #pragma unroll
    for (int u = 0; u < 4; u++) {
        int dcol = t + u * 256;
        int k = dcol & 511;
        float invf = expf(-((float)k) * (1.0f / 512.0f) * 9.210340371976184f);
        float a = p * invf;
        pos[j * DM + dcol] = (dcol < 512) ? sinf(a) : cosf(a);
    }
}

// ---------------------------------------------------------------------------
// Embedding gather: out[row,:] = emb[data[row],:]
__global__ __launch_bounds__(256) void gather_emb(const int* __restrict__ data,
                                                  const float* __restrict__ emb,
                                                  float* __restrict__ out) {
    int row = blockIdx.x;
    int t = threadIdx.x;
    int tok = data[row];
    const float4* src = (const float4*)(emb + (size_t)tok * DM);
    float4* dst = (float4*)(out + (size_t)row * DM);
    dst[t] = src[t];
}

// ---------------------------------------------------------------------------
// SGEMM: C[M,N] = A[M,K] @ B[K,N] (+bias) (+relu). 64x64 tile, BK=16,
// 256 threads, 4x4 microtile. M,N multiples of 64; K multiple of 16.
template <bool BIAS, bool RELU>
__global__ __launch_bounds__(256) void sgemm_kernel(const float* __restrict__ A,
                                                    const float* __restrict__ B,
                                                    const float* __restrict__ bias,
                                                    float* __restrict__ C,
                                                    int K, int N) {
    __shared__ float As[16][64];
    __shared__ float Bs[16][64];
    int t = threadIdx.x;
    int bm = blockIdx.y * 64, bn = blockIdx.x * 64;
    int ty = t >> 4, tx = t & 15;
    int rm = ty * 4, rn = tx * 4;
    float acc[4][4] = {};

    int am = t >> 2, ak = (t & 3) << 2;        // A loader: row am, 4 cols at ak
    int bk = t >> 4, bn2 = (t & 15) << 2;      // B loader: row bk, 4 cols at bn2
    const float* Aptr = A + (size_t)(bm + am) * K + ak;
    const float* Bptr = B + (size_t)bk * N + bn + bn2;

    for (int kt = 0; kt < K; kt += 16) {
        float4 av = *(const float4*)(Aptr + kt);
        float4 bv = *(const float4*)(Bptr + (size_t)kt * N);
        As[ak + 0][am] = av.x;
        As[ak + 1][am] = av.y;
        As[ak + 2][am] = av.z;
        As[ak + 3][am] = av.w;
        *(float4*)&Bs[bk][bn2] = bv;
        __syncthreads();
        #pragma unroll
        for (int kk = 0; kk < 16; kk++) {
            float4 a = *(const float4*)&As[kk][rm];
            float4 b = *(const float4*)&Bs[kk][rn];
            float aa[4] = {a.x, a.y, a.z, a.w};
            float bb[4] = {b.x, b.y, b.z, b.w};
            #pragma unroll
            for (int mi = 0; mi < 4; mi++)
                #pragma unroll
                for (int ni = 0; ni < 4; ni++)
                    acc[mi][ni] += aa[mi] * bb[ni];
        }
        __syncthreads();
    }

    #pragma unroll
    for (int mi = 0; mi < 4; mi++) {
        float4 sv;
        float v0 = acc[mi][0], v1 = acc[mi][1], v2 = acc[mi][2], v3 = acc[mi][3];
        if (BIAS) {
            v0 += bias[bn + rn + 0];
            v1 += bias[bn + rn + 1];
            v2 += bias[bn + rn + 2];
            v3 += bias[bn + rn + 3];
        }
        if (RELU) {
            v0 = fmaxf(v0, 0.f); v1 = fmaxf(v1, 0.f);
            v2 = fmaxf(v2, 0.f); v3 = fmaxf(v3, 0.f);
        }
        sv.x = v0; sv.y = v1; sv.z = v2; sv.w = v3;
        *(float4*)&C[(size_t)(bm + rm + mi) * N + bn + rn] = sv;
    }
}

// ---------------------------------------------------------------------------
// Fused attention: per (i, b, n) block computes scores (AC+BD, masked),
// softmax over klen=1024, then vec = prob @ v.
// q:   [qlen*bsz, NH*DH]   (row = i*8+b, col = n*64+d)
// kv:  [klen*bsz, 2*NH*DH] (k at n*64+d, v at 1024+n*64+d)
// rk:  [klen, NH*DH]
__global__ __launch_bounds__(256) void attn_kernel(const float* __restrict__ qb,
                                                   const float* __restrict__ kvb,
                                                   const float* __restrict__ rkb,
                                                   const float* __restrict__ rwb,
                                                   const float* __restrict__ rrb,
                                                   float* __restrict__ vecb) {
    int i = blockIdx.x, b = blockIdx.y, n = blockIdx.z;
    int t = threadIdx.x;
    __shared__ float qw[64], qr[64];
    __shared__ float sc[1024];
    __shared__ float vp[4][64];
    __shared__ float red[256];

    if (t < 64) {
        float qv = qb[(size_t)(i * 8 + b) * 1024 + n * 64 + t];
        qw[t] = qv + rwb[n * 64 + t];
        qr[t] = qv + rrb[n * 64 + t];
    }
    __syncthreads();

    float lmax = -1e30f;
    #pragma unroll
    for (int u = 0; u < 4; u++) {
        int j = t + u * 256;
        float s;
        if (j <= i + MLEN) {
            const float4* kp = (const float4*)(kvb + (size_t)(j * 8 + b) * 2048 + n * 64);
            const float4* rp = (const float4*)(rkb + (size_t)(j + QLEN - 1 - i) * 1024 + n * 64);
            float ac = 0.f, bd = 0.f;
            #pragma unroll
            for (int d4 = 0; d4 < 16; d4++) {
                float4 k4 = kp[d4];
                float4 r4 = rp[d4];
                const float* qwp = &qw[d4 * 4];
                const float* qrp = &qr[d4 * 4];
                ac += qwp[0] * k4.x + qwp[1] * k4.y + qwp[2] * k4.z + qwp[3] * k4.w;
                bd += qrp[0] * r4.x + qrp[1] * r4.y + qrp[2] * r4.z + qrp[3] * r4.w;
            }
            s = (ac + bd) * 0.125f;
        } else {
            s = -1e30f;
        }
        sc[j] = s;
        lmax = fmaxf(lmax, s);
    }
    red[t] = lmax;
    __syncthreads();
    for (int off = 128; off > 0; off >>= 1) {
        if (t < off) red[t] = fmaxf(red[t], red[t + off]);
        __syncthreads();
    }
    float M = red[0];
    __syncthreads();

    float lsum = 0.f;
    #pragma unroll
    for (int u = 0; u < 4; u++) {
        int j = t + u * 256;
        float e = __expf(sc[j] - M);
        sc[j] = e;
        lsum += e;
    }
    red[t] = lsum;
    __syncthreads();
    for (int off = 128; off > 0; off >>= 1) {
        if (t < off) red[t] += red[t + off];
        __syncthreads();
    }
    float inv = 1.0f / red[0];
    __syncthreads();

    // vec = prob @ v : thread (c,d) sums 256 j's
    int d = t & 63, c = t >> 6;
    float acc = 0.f;
    const float* vb = kvb + 1024 + n * 64 + d;
    int j0 = c * 256;
    for (int j = j0; j < j0 + 256; j++) acc += sc[j] * vb[(size_t)(j * 8 + b) * 2048];
    vp[c][d] = acc;
    __syncthreads();
    if (t < 64)
        vecb[(size_t)(i * 8 + b) * 1024 + n * 64 + t] =
            (vp[0][t] + vp[1][t] + vp[2][t] + vp[3][t]) * inv;
}

// ---------------------------------------------------------------------------
// Residual add + LayerNorm (population var), row = blockIdx.x over 1024 cols
__global__ __launch_bounds__(256) void add_ln_kernel(const float* __restrict__ x,
                                                     const float* __restrict__ y,
                                                     const float* __restrict__ g,
                                                     const float* __restrict__ bb,
                                                     float* __restrict__ out) {
    int row = blockIdx.x;
    int t = threadIdx.x;
    __shared__ float rs[256], rq[256];
    float v[4];
    float s = 0.f, sq = 0.f;
    #pragma unroll
    for (int u = 0; u < 4; u++) {
        int c = t + u * 256;
        float val = x[(size_t)row * DM + c] + y[(size_t)row * DM + c];
        v[u] = val;
        s += val;
        sq += val * val;
    }
    rs[t] = s;
    rq[t] = sq;
    __syncthreads();
    for (int off = 128; off > 0; off >>= 1) {
        if (t < off) { rs[t] += rs[t + off]; rq[t] += rq[t + off]; }
        __syncthreads();
    }
    float mu = rs[0] * (1.0f / 1024.0f);
    float var = rq[0] * (1.0f / 1024.0f) - mu * mu;
    float rstd = rsqrtf(var + 1e-5f);
    #pragma unroll
    for (int u = 0; u < 4; u++) {
        int c = t + u * 256;
        out[(size_t)row * DM + c] = (v[u] - mu) * rstd * g[c] + bb[c];
    }
}

// ---------------------------------------------------------------------------
// Target logit: ltgt[row] = dot(core[row,:], emb[target[row],:])
__global__ __launch_bounds__(256) void tgt_logit_kernel(const float* __restrict__ core,
                                                        const float* __restrict__ emb,
                                                        const int* __restrict__ target,
                                                        float* __restrict__ out) {
    int row = blockIdx.x;
    int t = threadIdx.x;
    __shared__ float red[256];
    int tok = target[row];
    const float* a = core + (size_t)row * DM;
    const float* e = emb + (size_t)tok * DM;
    float s = 0.f;
    #pragma unroll
    for (int u = 0; u < 4; u++) {
        int c = t + u * 256;
        s += a[c] * e[c];
    }
    red[t] = s;
    __syncthreads();
    for (int off = 128; off > 0; off >>= 1) {
        if (t < off) red[t] += red[t + off];
        __syncthreads();
    }
    if (t == 0) out[row] = red[0];
}

// ---------------------------------------------------------------------------
// Logits GEMM + per-tile partial LSE.  A[4096,1024] @ E^T, E[32000,1024].
// Each block: 64 rows x 64 vocab; emits pmax/psum[row*VTILES + vtile].
__global__ __launch_bounds__(256) void lse_gemm_kernel(const float* __restrict__ A,
                                                       const float* __restrict__ E,
                                                       float* __restrict__ pmax,
                                                       float* __restrict__ psum) {
    __shared__ float As[16][64];
    __shared__ float Bs[64][17];
    __shared__ float redm[64][17];
    __shared__ float rmax[64];
    int t = threadIdx.x;
    int bm = blockIdx.y * 64, bv = blockIdx.x * 64;
    int ty = t >> 4, tx = t & 15;
    int rm = ty * 4;
    float acc[4][4] = {};

    int lm = t >> 2, lk = (t & 3) << 2;
    for (int kt = 0; kt < 1024; kt += 16) {
        float4 av = *(const float4*)(A + (size_t)(bm + lm) * 1024 + kt + lk);
        As[lk + 0][lm] = av.x;
        As[lk + 1][lm] = av.y;
        As[lk + 2][lm] = av.z;
        As[lk + 3][lm] = av.w;
        float4 ev = *(const float4*)(E + (size_t)(bv + lm) * 1024 + kt + lk);
        Bs[lm][lk + 0] = ev.x;
        Bs[lm][lk + 1] = ev.y;
        Bs[lm][lk + 2] = ev.z;
        Bs[lm][lk + 3] = ev.w;
        __syncthreads();
        #pragma unroll
        for (int kk = 0; kk < 16; kk++) {
            float4 a = *(const float4*)&As[kk][rm];
            float aa[4] = {a.x, a.y, a.z, a.w};
            float bbv[4];
            #pragma unroll
            for (int vi = 0; vi < 4; vi++) bbv[vi] = Bs[tx * 4 + vi][kk];
            #pragma unroll
            for (int mi = 0; mi < 4; mi++)
                #pragma unroll
                for (int vi = 0; vi < 4; vi++) acc[mi][vi] += aa[mi] * bbv[vi];
        }
        __syncthreads();
    }

    // per-row max over the 64-vocab tile
    #pragma unroll
    for (int mi = 0; mi < 4; mi++) {
        float m = fmaxf(fmaxf(acc[mi][0], acc[mi][1]), fmaxf(acc[mi][2], acc[mi][3]));
        redm[rm + mi][tx] = m;
    }
    __syncthreads();
    if (t < 64) {
        float m = -1e30f;
        #pragma unroll
        for (int x = 0; x < 16; x++) m = fmaxf(m, redm[t][x]);
        rmax[t] = m;
    }
    __syncthreads();
    #pragma unroll
    for (int mi = 0; mi < 4; mi++) {
        float m = rmax[rm + mi];
        float s = __expf(acc[mi][0] - m) + __expf(acc[mi][1] - m) +
                  __expf(acc[mi][2] - m) + __expf(acc[mi][3] - m);
        redm[rm + mi][tx] = s;
    }
    __syncthreads();
    if (t < 64) {
        float s = 0.f;
        #pragma unroll
        for (int x = 0; x < 16; x++) s += redm[t][x];
        int grow = bm + t;
        pmax[(size_t)grow * VTILES + blockIdx.x] = rmax[t];
        psum[(size_t)grow * VTILES + blockIdx.x] = s;
    }
}

// ---------------------------------------------------------------------------
// Final LSE reduce: loss[row] = max + log(sum) - ltgt[row]
__global__ __launch_bounds__(256) void lse_reduce_kernel(const float* __restrict__ pmax,
                                                         const float* __restrict__ psum,
                                                         const float* __restrict__ ltgt,
                                                         float* __restrict__ loss) {
    int row = blockIdx.x;
    int t = threadIdx.x;
    __shared__ float red[256];
    float m = -1e30f;
    for (int u = t; u < VTILES; u += 256) m = fmaxf(m, pmax[(size_t)row * VTILES + u]);
    red[t] = m;
    __syncthreads();
    for (int off = 128; off > 0; off >>= 1) {
        if (t < off) red[t] = fmaxf(red[t], red[t + off]);
        __syncthreads();
    }
    float M = red[0];
    __syncthreads();
    float s = 0.f;
    for (int u = t; u < VTILES; u += 256)
        s += psum[(size_t)row * VTILES + u] * __expf(pmax[(size_t)row * VTILES + u] - M);
    red[t] = s;
    __syncthreads();
    for (int off = 128; off > 0; off >>= 1) {
        if (t < off) red[t] += red[t + off];
        __syncthreads();
    }
    if (t == 0) loss[row] = M + logf(red[0]) - ltgt[row];
}

// ---------------------------------------------------------------------------
extern "C" void kernel_launch(void* const* d_in, const int* in_sizes, int n_in,
                              void* d_out, int out_size, void* d_ws, size_t ws_size,
                              hipStream_t stream) {
    const int*   data   = (const int*)d_in[0];
    const int*   target = (const int*)d_in[1];
    const float* memory = (const float*)d_in[2];
    const float* embW   = (const float*)d_in[3];
    const float* rwb    = (const float*)d_in[4];
    const float* rrb    = (const float*)d_in[5];
    const float* Wq     = (const float*)d_in[6];
    const float* Wkv    = (const float*)d_in[7];
    const float* Wr     = (const float*)d_in[8];
    const float* Wo     = (const float*)d_in[9];
    const float* W1     = (const float*)d_in[10];
    const float* b1     = (const float*)d_in[11];
    const float* W2     = (const float*)d_in[12];
    const float* b2     = (const float*)d_in[13];
    const float* ln1g   = (const float*)d_in[14];
    const float* ln1b   = (const float*)d_in[15];
    const float* ln2g   = (const float*)d_in[16];
    const float* ln2b   = (const float*)d_in[17];

    float* out  = (float*)d_out;
    float* loss = out;                 // [512,8]
    float* hids = out + 4096;          // 6 x [512,8,1024] = new_mems

    const size_t SZ_CORE = (size_t)NROW * DM;      // 4194304
    const size_t SZ_POS  = (size_t)KLEN * DM;      // 1048576
    const size_t SZ_KV   = (size_t)XROW * 2 * DM;  // 16777216
    const size_t SZ_BIG  = (size_t)NROW * DI;      // 16777216 (xmem / h1)

    float* ws   = (float*)d_ws;
    float* pos  = ws;
    float* qbuf = pos + SZ_POS;
    float* rk   = qbuf + SZ_CORE;
    float* kv   = rk + SZ_POS;
    float* big  = kv + SZ_KV;          // xmem (8192x1024) then h1 (4096x4096)
    float* vec  = big + SZ_BIG;
    float* tmp  = vec + SZ_CORE;
    float* cmid = tmp + SZ_CORE;
    // aliases (used only after all layers are done / after attention of L5):
    float* ltgt    = qbuf;
    float* pmax    = qbuf + 4096;
    float* psum    = pmax + (size_t)NROW * VTILES;
    float* corefin = vec;

    pos_kernel<<<KLEN, 256, 0, stream>>>(pos);
    gather_emb<<<NROW, 256, 0, stream>>>(data, embW, hids);  // hids[0] = word_emb

    for (int L = 0; L < 6; L++) {
        const float* cin = hids + (size_t)L * SZ_CORE;
        float* cout = (L < 5) ? (hids + (size_t)(L + 1) * SZ_CORE) : corefin;

        // q = cin @ Wq[L]
        sgemm_kernel<false, false><<<dim3(16, 64), 256, 0, stream>>>(
            cin, Wq + (size_t)L * DM * DM, nullptr, qbuf, DM, DM);

        // x_mem = concat(mem[L], cin)
        hipMemcpyAsync(big, memory + (size_t)L * SZ_CORE, SZ_CORE * sizeof(float),
                       hipMemcpyDeviceToDevice, stream);
        hipMemcpyAsync(big + SZ_CORE, cin, SZ_CORE * sizeof(float),
                       hipMemcpyDeviceToDevice, stream);

        // kv = x_mem @ Wkv[L]   (M=8192, K=1024, N=2048)
        sgemm_kernel<false, false><<<dim3(32, 128), 256, 0, stream>>>(
            big, Wkv + (size_t)L * DM * 2 * DM, nullptr, kv, DM, 2 * DM);

        // r_k = pos @ Wr[L]     (M=1024)
        sgemm_kernel<false, false><<<dim3(16, 16), 256, 0, stream>>>(
            pos, Wr + (size_t)L * DM * DM, nullptr, rk, DM, DM);

        // fused attention -> vec
        attn_kernel<<<dim3(QLEN, BSZ, NH), 256, 0, stream>>>(qbuf, kv, rk, rwb, rrb, vec);

        // attn_out = vec @ Wo[L]
        sgemm_kernel<false, false><<<dim3(16, 64), 256, 0, stream>>>(
            vec, Wo + (size_t)L * DM * DM, nullptr, tmp, DM, DM);

        // core_mid = LN(cin + attn_out)
        add_ln_kernel<<<NROW, 256, 0, stream>>>(cin, tmp, ln1g + L * DM, ln1b + L * DM, cmid);

        // h1 = relu(core_mid @ W1[L] + b1[L])   (N=4096)
        sgemm_kernel<true, true><<<dim3(64, 64), 256, 0, stream>>>(
            cmid, W1 + (size_t)L * DM * DI, b1 + (size_t)L * DI, big, DM, DI);

        // ff = h1 @ W2[L] + b2[L]               (K=4096)
        sgemm_kernel<true, false><<<dim3(16, 64), 256, 0, stream>>>(
            big, W2 + (size_t)L * DI * DM, b2 + (size_t)L * DM, tmp, DI, DM);

        // core_out = LN(core_mid + ff)
        add_ln_kernel<<<NROW, 256, 0, stream>>>(cmid, tmp, ln2g + L * DM, ln2b + L * DM, cout);
    }

    // loss = logsumexp(core @ embW^T) - logit[target]
    tgt_logit_kernel<<<NROW, 256, 0, stream>>>(corefin, embW, target, ltgt);
    lse_gemm_kernel<<<dim3(VTILES, 64), 256, 0, stream>>>(corefin, embW, pmax, psum);
    lse_reduce_kernel<<<NROW, 256, 0, stream>>>(pmax, psum, ltgt, loss);
}

// Round 2
// 22108.359 us; speedup vs baseline: 1.6111x; 1.6111x over previous
//
#include <hip/hip_runtime.h>
#include <hip/hip_bf16.h>
#include <math.h>

// Problem constants
#define QLEN   512
#define MLEN   512
#define KLEN   1024
#define BSZ    8
#define NH     16
#define DH     64
#define DM     1024
#define DI     4096
#define NTOK   32000
#define NROW   4096      // QLEN*BSZ
#define XROW   8192      // KLEN*BSZ
#define VTILES 500       // 32000/64

typedef __hip_bfloat16 bf16;
typedef __attribute__((ext_vector_type(8))) short bf16x8;
typedef __attribute__((ext_vector_type(4))) float f32x4;

__device__ __forceinline__ unsigned short f2b(float x) {
    union { float f; unsigned u; } a; a.f = x;
    unsigned r = a.u + 0x7fffu + ((a.u >> 16) & 1u);
    return (unsigned short)(r >> 16);
}
__device__ __forceinline__ float b2f(unsigned short h) {
    union { unsigned u; float f; } a; a.u = ((unsigned)h) << 16;
    return a.f;
}

__device__ __forceinline__ void gload_lds16(const void* g, void* l) {
    __builtin_amdgcn_global_load_lds(
        (const __attribute__((address_space(1))) unsigned int*)g,
        (__attribute__((address_space(3))) unsigned int*)l, 16, 0, 0);
}

// ---------------------------------------------------------------------------
// Positional embedding directly in bf16: pos[j,d], pos_seq[j]=1023-j
__global__ __launch_bounds__(256) void posb_kernel(unsigned short* __restrict__ posb) {
    int j = blockIdx.x;
    int t = threadIdx.x;
    float p = (float)(1023 - j);
    #pragma unroll
    for (int u = 0; u < 4; u++) {
        int dcol = t + u * 256;
        int k = dcol & 511;
        float invf = expf(-((float)k) * (1.0f / 512.0f) * 9.210340371976184f);
        float a = p * invf;
        posb[j * DM + dcol] = f2b((dcol < 512) ? sinf(a) : cosf(a));
    }
}

// ---------------------------------------------------------------------------
// Embedding gather: out[row,:] = emb[data[row],:]  (fp32 -> fp32, part of new_mems)
__global__ __launch_bounds__(256) void gather_emb(const int* __restrict__ data,
                                                  const float* __restrict__ emb,
                                                  float* __restrict__ out) {
    int row = blockIdx.x;
    int t = threadIdx.x;
    int tok = data[row];
    const float4* src = (const float4*)(emb + (size_t)tok * DM);
    float4* dst = (float4*)(out + (size_t)row * DM);
    dst[t] = src[t];
}

// ---------------------------------------------------------------------------
// fp32 -> bf16 cast, 4 elems/thread
__global__ __launch_bounds__(256) void cast_bf16(const float* __restrict__ src,
                                                 unsigned short* __restrict__ dst, int n4) {
    int i = blockIdx.x * 256 + threadIdx.x;
    if (i < n4) {
        float4 v = ((const float4*)src)[i];
        ushort4 o;
        o.x = f2b(v.x); o.y = f2b(v.y); o.z = f2b(v.z); o.w = f2b(v.w);
        ((ushort4*)dst)[i] = o;
    }
}

// ---------------------------------------------------------------------------
// fp32 [K,N] -> bf16 [N,K] transpose+cast. grid (N/32, K/32), block 256.
__global__ __launch_bounds__(256) void castT_kernel(const float* __restrict__ src,
                                                    unsigned short* __restrict__ dst,
                                                    int K, int N) {
    __shared__ float T[32][33];
    int t = threadIdx.x;
    int k0 = blockIdx.y * 32, n0 = blockIdx.x * 32;
    int r = t >> 3, c4 = (t & 7) * 4;
    float4 v = *(const float4*)(src + (size_t)(k0 + r) * N + n0 + c4);
    T[r][c4 + 0] = v.x; T[r][c4 + 1] = v.y; T[r][c4 + 2] = v.z; T[r][c4 + 3] = v.w;
    __syncthreads();
    ushort4 o;
    o.x = f2b(T[c4 + 0][r]); o.y = f2b(T[c4 + 1][r]);
    o.z = f2b(T[c4 + 2][r]); o.w = f2b(T[c4 + 3][r]);
    *(ushort4*)(dst + (size_t)(n0 + r) * K + k0 + c4) = o;
}

// ---------------------------------------------------------------------------
// bf16 MFMA GEMM: C[M,N] = A[M,K] @ B[N,K]^T. Both operands K-major bf16.
// 128x128 tile, BK=32, 256 threads (4 waves), each wave 64x64 via 4x4 of
// 16x16x32 MFMA. M,N multiples of 128, K multiple of 32.
template <bool BIAS, bool RELU, bool OUTBF16>
__global__ __launch_bounds__(256) void gemm_bt(const unsigned short* __restrict__ A,
                                               const unsigned short* __restrict__ B,
                                               const float* __restrict__ bias,
                                               void* __restrict__ Cout,
                                               int M, int N, int K) {
    __shared__ unsigned short As[128 * 32];
    __shared__ unsigned short Bs[128 * 32];
    int t = threadIdx.x;
    int wave = t >> 6, lane = t & 63;
    int bm = blockIdx.y * 128, bn = blockIdx.x * 128;
    int wm = (wave >> 1) * 64, wn = (wave & 1) * 64;
    int quad = lane >> 4, l16 = lane & 15;

    f32x4 acc[4][4] = {};

    int srow = wave * 32 + (lane >> 2);
    int scol = (lane & 3) * 8;
    const unsigned short* Ag = A + (size_t)(bm + srow) * K + scol;
    const unsigned short* Bg = B + (size_t)(bn + srow) * K + scol;
    unsigned short* Al0 = As + (wave * 32) * 32;
    unsigned short* Al1 = As + (wave * 32 + 16) * 32;
    unsigned short* Bl0 = Bs + (wave * 32) * 32;
    unsigned short* Bl1 = Bs + (wave * 32 + 16) * 32;

    for (int kt = 0; kt < K; kt += 32) {
        gload_lds16(Ag + kt, Al0);
        gload_lds16(Ag + kt + (size_t)16 * K, Al1);
        gload_lds16(Bg + kt, Bl0);
        gload_lds16(Bg + kt + (size_t)16 * K, Bl1);
        __syncthreads();
        bf16x8 af[4], bfr[4];
        #pragma unroll
        for (int mi = 0; mi < 4; mi++)
            af[mi] = *(const bf16x8*)&As[(wm + mi * 16 + l16) * 32 + quad * 8];
        #pragma unroll
        for (int ni = 0; ni < 4; ni++)
            bfr[ni] = *(const bf16x8*)&Bs[(wn + ni * 16 + l16) * 32 + quad * 8];
        #pragma unroll
        for (int mi = 0; mi < 4; mi++)
            #pragma unroll
            for (int ni = 0; ni < 4; ni++)
                acc[mi][ni] = __builtin_amdgcn_mfma_f32_16x16x32_bf16(
                    af[mi], bfr[ni], acc[mi][ni], 0, 0, 0);
        __syncthreads();
    }

    #pragma unroll
    for (int mi = 0; mi < 4; mi++) {
        #pragma unroll
        for (int ni = 0; ni < 4; ni++) {
            int c = bn + wn + ni * 16 + l16;
            float bv = BIAS ? bias[c] : 0.0f;
            #pragma unroll
            for (int reg = 0; reg < 4; reg++) {
                int r = bm + wm + mi * 16 + quad * 4 + reg;
                float x = acc[mi][ni][reg];
                if (BIAS) x += bv;
                if (RELU) x = fmaxf(x, 0.0f);
                if (OUTBF16) ((unsigned short*)Cout)[(size_t)r * N + c] = f2b(x);
                else         ((float*)Cout)[(size_t)r * N + c] = x;
            }
        }
    }
}

// ---------------------------------------------------------------------------
// Fused logits + partial LSE, MFMA version. A[4096,1024]bf16, B=embW[32000,1024]bf16.
// Grid (250, 32): 128 rows x 128 vocab per block. Emits per-(row, 64-vocab-tile)
// pmax/psum, vtile = blockIdx.x*2 + (wave&1).
__global__ __launch_bounds__(256) void lse_gemm_mfma(const unsigned short* __restrict__ A,
                                                     const unsigned short* __restrict__ B,
                                                     float* __restrict__ pmax,
                                                     float* __restrict__ psum) {
    __shared__ unsigned short As[128 * 32];
    __shared__ unsigned short Bs[128 * 32];
    int t = threadIdx.x;
    int wave = t >> 6, lane = t & 63;
    int bm = blockIdx.y * 128, bn = blockIdx.x * 128;
    int wm = (wave >> 1) * 64;
    int quad = lane >> 4, l16 = lane & 15;
    const int K = 1024;

    f32x4 acc[4][4] = {};

    int srow = wave * 32 + (lane >> 2);
    int scol = (lane & 3) * 8;
    const unsigned short* Ag = A + (size_t)(bm + srow) * K + scol;
    const unsigned short* Bg = B + (size_t)(bn + srow) * K + scol;
    unsigned short* Al0 = As + (wave * 32) * 32;
    unsigned short* Al1 = As + (wave * 32 + 16) * 32;
    unsigned short* Bl0 = Bs + (wave * 32) * 32;
    unsigned short* Bl1 = Bs + (wave * 32 + 16) * 32;
    int wn = (wave & 1) * 64;

    for (int kt = 0; kt < K; kt += 32) {
        gload_lds16(Ag + kt, Al0);
        gload_lds16(Ag + kt + (size_t)16 * K, Al1);
        gload_lds16(Bg + kt, Bl0);
        gload_lds16(Bg + kt + (size_t)16 * K, Bl1);
        __syncthreads();
        bf16x8 af[4], bfr[4];
        #pragma unroll
        for (int mi = 0; mi < 4; mi++)
            af[mi] = *(const bf16x8*)&As[(wm + mi * 16 + l16) * 32 + quad * 8];
        #pragma unroll
        for (int ni = 0; ni < 4; ni++)
            bfr[ni] = *(const bf16x8*)&Bs[(wn + ni * 16 + l16) * 32 + quad * 8];
        #pragma unroll
        for (int mi = 0; mi < 4; mi++)
            #pragma unroll
            for (int ni = 0; ni < 4; ni++)
                acc[mi][ni] = __builtin_amdgcn_mfma_f32_16x16x32_bf16(
                    af[mi], bfr[ni], acc[mi][ni], 0, 0, 0);
        __syncthreads();
    }

    // per-row (over this wave's 64 cols) max & sumexp, then one write per row
    int vt = blockIdx.x * 2 + (wave & 1);
    #pragma unroll
    for (int mi = 0; mi < 4; mi++) {
        #pragma unroll
        for (int reg = 0; reg < 4; reg++) {
            float m = -1e30f;
            #pragma unroll
            for (int ni = 0; ni < 4; ni++) m = fmaxf(m, acc[mi][ni][reg]);
            #pragma unroll
            for (int off = 1; off < 16; off <<= 1) m = fmaxf(m, __shfl_xor(m, off, 64));
            float s = 0.0f;
            #pragma unroll
            for (int ni = 0; ni < 4; ni++) s += __expf(acc[mi][ni][reg] - m);
            #pragma unroll
            for (int off = 1; off < 16; off <<= 1) s += __shfl_xor(s, off, 64);
            if (l16 == 0) {
                int r = bm + wm + mi * 16 + quad * 4 + reg;
                pmax[(size_t)r * VTILES + vt] = m;
                psum[(size_t)r * VTILES + vt] = s;
            }
        }
    }
}

// ---------------------------------------------------------------------------
// Fused attention (fp32): per (i,b,n) block: scores, softmax, prob@v.
__global__ __launch_bounds__(256) void attn_kernel(const float* __restrict__ qb,
                                                   const float* __restrict__ kvb,
                                                   const float* __restrict__ rkb,
                                                   const float* __restrict__ rwb,
                                                   const float* __restrict__ rrb,
                                                   float* __restrict__ vecb) {
    int i = blockIdx.x, b = blockIdx.y, n = blockIdx.z;
    int t = threadIdx.x;
    __shared__ float qw[64], qr[64];
    __shared__ float sc[1024];
    __shared__ float vp[4][64];
    __shared__ float red[256];

    if (t < 64) {
        float qv = qb[(size_t)(i * 8 + b) * 1024 + n * 64 + t];
        qw[t] = qv + rwb[n * 64 + t];
        qr[t] = qv + rrb[n * 64 + t];
    }
    __syncthreads();

    float lmax = -1e30f;
    #pragma unroll
    for (int u = 0; u < 4; u++) {
        int j = t + u * 256;
        float s;
        if (j <= i + MLEN) {
            const float4* kp = (const float4*)(kvb + (size_t)(j * 8 + b) * 2048 + n * 64);
            const float4* rp = (const float4*)(rkb + (size_t)(j + QLEN - 1 - i) * 1024 + n * 64);
            float ac = 0.f, bd = 0.f;
            #pragma unroll
            for (int d4 = 0; d4 < 16; d4++) {
                float4 k4 = kp[d4];
                float4 r4 = rp[d4];
                const float* qwp = &qw[d4 * 4];
                const float* qrp = &qr[d4 * 4];
                ac += qwp[0] * k4.x + qwp[1] * k4.y + qwp[2] * k4.z + qwp[3] * k4.w;
                bd += qrp[0] * r4.x + qrp[1] * r4.y + qrp[2] * r4.z + qrp[3] * r4.w;
            }
            s = (ac + bd) * 0.125f;
        } else {
            s = -1e30f;
        }
        sc[j] = s;
        lmax = fmaxf(lmax, s);
    }
    red[t] = lmax;
    __syncthreads();
    for (int off = 128; off > 0; off >>= 1) {
        if (t < off) red[t] = fmaxf(red[t], red[t + off]);
        __syncthreads();
    }
    float M = red[0];
    __syncthreads();

    float lsum = 0.f;
    #pragma unroll
    for (int u = 0; u < 4; u++) {
        int j = t + u * 256;
        float e = __expf(sc[j] - M);
        sc[j] = e;
        lsum += e;
    }
    red[t] = lsum;
    __syncthreads();
    for (int off = 128; off > 0; off >>= 1) {
        if (t < off) red[t] += red[t + off];
        __syncthreads();
    }
    float inv = 1.0f / red[0];
    __syncthreads();

    int d = t & 63, c = t >> 6;
    float acc = 0.f;
    const float* vb = kvb + 1024 + n * 64 + d;
    int j0 = c * 256;
    for (int j = j0; j < j0 + 256; j++) acc += sc[j] * vb[(size_t)(j * 8 + b) * 2048];
    vp[c][d] = acc;
    __syncthreads();
    if (t < 64)
        vecb[(size_t)(i * 8 + b) * 1024 + n * 64 + t] =
            (vp[0][t] + vp[1][t] + vp[2][t] + vp[3][t]) * inv;
}

// ---------------------------------------------------------------------------
// Residual add + LayerNorm
__global__ __launch_bounds__(256) void add_ln_kernel(const float* __restrict__ x,
                                                     const float* __restrict__ y,
                                                     const float* __restrict__ g,
                                                     const float* __restrict__ bb,
                                                     float* __restrict__ out) {
    int row = blockIdx.x;
    int t = threadIdx.x;
    __shared__ float rs[256], rq[256];
    float v[4];
    float s = 0.f, sq = 0.f;
    #pragma unroll
    for (int u = 0; u < 4; u++) {
        int c = t + u * 256;
        float val = x[(size_t)row * DM + c] + y[(size_t)row * DM + c];
        v[u] = val;
        s += val;
        sq += val * val;
    }
    rs[t] = s;
    rq[t] = sq;
    __syncthreads();
    for (int off = 128; off > 0; off >>= 1) {
        if (t < off) { rs[t] += rs[t + off]; rq[t] += rq[t + off]; }
        __syncthreads();
    }
    float mu = rs[0] * (1.0f / 1024.0f);
    float var = rq[0] * (1.0f / 1024.0f) - mu * mu;
    float rstd = rsqrtf(var + 1e-5f);
    #pragma unroll
    for (int u = 0; u < 4; u++) {
        int c = t + u * 256;
        out[(size_t)row * DM + c] = (v[u] - mu) * rstd * g[c] + bb[c];
    }
}

// ---------------------------------------------------------------------------
// Target logit from bf16 operands
__global__ __launch_bounds__(256) void tgt_logit_bf(const unsigned short* __restrict__ core,
                                                    const unsigned short* __restrict__ emb,
                                                    const int* __restrict__ target,
                                                    float* __restrict__ out) {
    int row = blockIdx.x;
    int t = threadIdx.x;
    __shared__ float red[256];
    int tok = target[row];
    const unsigned short* a = core + (size_t)row * DM;
    const unsigned short* e = emb + (size_t)tok * DM;
    float s = 0.f;
    #pragma unroll
    for (int u = 0; u < 4; u++) {
        int c = t + u * 256;
        s += b2f(a[c]) * b2f(e[c]);
    }
    red[t] = s;
    __syncthreads();
    for (int off = 128; off > 0; off >>= 1) {
        if (t < off) red[t] += red[t + off];
        __syncthreads();
    }
    if (t == 0) out[row] = red[0];
}

// ---------------------------------------------------------------------------
// Final LSE reduce: loss[row] = max + log(sum) - ltgt[row]
__global__ __launch_bounds__(256) void lse_reduce_kernel(const float* __restrict__ pmax,
                                                         const float* __restrict__ psum,
                                                         const float* __restrict__ ltgt,
                                                         float* __restrict__ loss) {
    int row = blockIdx.x;
    int t = threadIdx.x;
    __shared__ float red[256];
    float m = -1e30f;
    for (int u = t; u < VTILES; u += 256) m = fmaxf(m, pmax[(size_t)row * VTILES + u]);
    red[t] = m;
    __syncthreads();
    for (int off = 128; off > 0; off >>= 1) {
        if (t < off) red[t] = fmaxf(red[t], red[t + off]);
        __syncthreads();
    }
    float M = red[0];
    __syncthreads();
    float s = 0.f;
    for (int u = t; u < VTILES; u += 256)
        s += psum[(size_t)row * VTILES + u] * __expf(pmax[(size_t)row * VTILES + u] - M);
    red[t] = s;
    __syncthreads();
    for (int off = 128; off > 0; off >>= 1) {
        if (t < off) red[t] += red[t + off];
        __syncthreads();
    }
    if (t == 0) loss[row] = M + logf(red[0]) - ltgt[row];
}

// ---------------------------------------------------------------------------
extern "C" void kernel_launch(void* const* d_in, const int* in_sizes, int n_in,
                              void* d_out, int out_size, void* d_ws, size_t ws_size,
                              hipStream_t stream) {
    const int*   data   = (const int*)d_in[0];
    const int*   target = (const int*)d_in[1];
    const float* memory = (const float*)d_in[2];
    const float* embW   = (const float*)d_in[3];
    const float* rwb    = (const float*)d_in[4];
    const float* rrb    = (const float*)d_in[5];
    const float* Wq     = (const float*)d_in[6];
    const float* Wkv    = (const float*)d_in[7];
    const float* Wr     = (const float*)d_in[8];
    const float* Wo     = (const float*)d_in[9];
    const float* W1     = (const float*)d_in[10];
    const float* b1     = (const float*)d_in[11];
    const float* W2     = (const float*)d_in[12];
    const float* b2     = (const float*)d_in[13];
    const float* ln1g   = (const float*)d_in[14];
    const float* ln1b   = (const float*)d_in[15];
    const float* ln2g   = (const float*)d_in[16];
    const float* ln2b   = (const float*)d_in[17];

    float* out  = (float*)d_out;
    float* loss = out;                 // [512,8]
    float* hids = out + 4096;          // 6 x [512,8,1024] = new_mems

    const size_t SZ_CORE = (size_t)NROW * DM;      // 4 Mi elems

    // Workspace layout (byte offsets; total 198 MiB)
    const size_t MB = 1024 * 1024;
    char* base = (char*)d_ws;
    unsigned short* posb  = (unsigned short*)(base);              //  2 MB, 1Mi bf16
    unsigned short* wT    = (unsigned short*)(base + 2  * MB);    //  8 MB, 4Mi bf16
    unsigned short* actb  = (unsigned short*)(base + 10 * MB);    //  8 MB, 4Mi bf16
    unsigned short* xmemb = (unsigned short*)(base + 18 * MB);    // 16 MB, 8Mi bf16
    float* qbuf = (float*)(base + 34  * MB);                      // 16 MB
    float* rk   = (float*)(base + 50  * MB);                      //  4 MB
    float* tmp  = (float*)(base + 54  * MB);                      // 16 MB
    float* cmid = (float*)(base + 70  * MB);                      // 16 MB
    float* vec  = (float*)(base + 86  * MB);                      // 16 MB
    float* kv   = (float*)(base + 102 * MB);                      // 64 MB
    unsigned short* h1b = (unsigned short*)(base + 166 * MB);     // 32 MB, 16Mi bf16
    // end-phase aliases:
    unsigned short* cinb    = xmemb + SZ_CORE;  // lower half of xmemb = cast(cin)
    unsigned short* embWb   = (unsigned short*)(base + 102 * MB); // 65.5MB over kv+h1b
    unsigned short* corefnb = actb;
    float* ltgt = rk;
    float* pmax = qbuf;   // 4096*500 floats = 8.2MB (fits in 16MB)
    float* psum = tmp;

    posb_kernel<<<KLEN, 256, 0, stream>>>(posb);
    gather_emb<<<NROW, 256, 0, stream>>>(data, embW, hids);  // hids[0] = word_emb

    for (int L = 0; L < 6; L++) {
        const float* cin = hids + (size_t)L * SZ_CORE;
        float* cout = (L < 5) ? (hids + (size_t)(L + 1) * SZ_CORE) : vec;

        // xmemb = bf16(concat(mem[L], cin))
        cast_bf16<<<4096, 256, 0, stream>>>(memory + (size_t)L * SZ_CORE, xmemb, 1 << 20);
        cast_bf16<<<4096, 256, 0, stream>>>(cin, cinb, 1 << 20);

        // q = cin @ Wq[L]  (fp32 out for attention)
        castT_kernel<<<dim3(32, 32), 256, 0, stream>>>(Wq + (size_t)L * DM * DM, wT, DM, DM);
        gemm_bt<false, false, false><<<dim3(8, 32), 256, 0, stream>>>(
            cinb, wT, nullptr, qbuf, NROW, DM, DM);

        // kv = x_mem @ Wkv[L]  (M=8192, N=2048)
        castT_kernel<<<dim3(64, 32), 256, 0, stream>>>(Wkv + (size_t)L * DM * 2 * DM, wT, DM, 2 * DM);
        gemm_bt<false, false, false><<<dim3(16, 64), 256, 0, stream>>>(
            xmemb, wT, nullptr, kv, XROW, 2 * DM, DM);

        // r_k = pos @ Wr[L]
        castT_kernel<<<dim3(32, 32), 256, 0, stream>>>(Wr + (size_t)L * DM * DM, wT, DM, DM);
        gemm_bt<false, false, false><<<dim3(8, 8), 256, 0, stream>>>(
            posb, wT, nullptr, rk, KLEN, DM, DM);

        // fused attention -> vec (fp32)
        attn_kernel<<<dim3(QLEN, BSZ, NH), 256, 0, stream>>>(qbuf, kv, rk, rwb, rrb, vec);

        // attn_out = vec @ Wo[L] -> tmp
        cast_bf16<<<4096, 256, 0, stream>>>(vec, actb, 1 << 20);
        castT_kernel<<<dim3(32, 32), 256, 0, stream>>>(Wo + (size_t)L * DM * DM, wT, DM, DM);
        gemm_bt<false, false, false><<<dim3(8, 32), 256, 0, stream>>>(
            actb, wT, nullptr, tmp, NROW, DM, DM);

        // core_mid = LN(cin + attn_out)
        add_ln_kernel<<<NROW, 256, 0, stream>>>(cin, tmp, ln1g + L * DM, ln1b + L * DM, cmid);

        // h1 = relu(core_mid @ W1[L] + b1[L]) -> bf16 directly
        cast_bf16<<<4096, 256, 0, stream>>>(cmid, actb, 1 << 20);
        castT_kernel<<<dim3(128, 32), 256, 0, stream>>>(W1 + (size_t)L * DM * DI, wT, DM, DI);
        gemm_bt<true, true, true><<<dim3(32, 32), 256, 0, stream>>>(
            actb, wT, b1 + (size_t)L * DI, h1b, NROW, DI, DM);

        // ff = h1 @ W2[L] + b2[L]  (K=4096)
        castT_kernel<<<dim3(32, 128), 256, 0, stream>>>(W2 + (size_t)L * DI * DM, wT, DI, DM);
        gemm_bt<true, false, false><<<dim3(8, 32), 256, 0, stream>>>(
            h1b, wT, b2 + (size_t)L * DM, tmp, NROW, DM, DI);

        // core_out = LN(core_mid + ff)
        add_ln_kernel<<<NROW, 256, 0, stream>>>(cmid, tmp, ln2g + L * DM, ln2b + L * DM, cout);
    }

    // Final: loss = LSE(core @ embW^T) - logit[target]
    cast_bf16<<<4096, 256, 0, stream>>>(vec, corefnb, 1 << 20);
    cast_bf16<<<32768, 256, 0, stream>>>(embW, embWb, (NTOK * DM) / 4);
    tgt_logit_bf<<<NROW, 256, 0, stream>>>(corefnb, embWb, target, ltgt);
    lse_gemm_mfma<<<dim3(250, 32), 256, 0, stream>>>(corefnb, embWb, pmax, psum);
    lse_reduce_kernel<<<NROW, 256, 0, stream>>>(pmax, psum, ltgt, loss);
}